// Round 1
// baseline (314.473 us; speedup 1.0000x reference)
//
#include <hip/hip_runtime.h>
#include <hip/hip_bf16.h>

#define DIM   1536
#define HEADS 12
#define HD    128
#define LSEQ  2048
#define NB    2
#define NTOK  (NB*LSEQ)   // 4096

using f32x4 = __attribute__((ext_vector_type(4))) float;
using s16x8 = __attribute__((ext_vector_type(8))) short;
using u16x4 = __attribute__((ext_vector_type(4))) unsigned short;

__device__ __forceinline__ unsigned short f2bf(float f) {
  unsigned int u = __builtin_bit_cast(unsigned int, f);
  u += 0x7fffu + ((u >> 16) & 1u);   // RNE
  return (unsigned short)(u >> 16);
}

__device__ __forceinline__ void gload_lds16(const void* g, void* l) {
  __builtin_amdgcn_global_load_lds(
      (__attribute__((address_space(1))) void*)const_cast<void*>(g),
      (__attribute__((address_space(3))) void*)l,
      16, 0, 0);
}

// ---------------- convert x -> bf16 ----------------
__global__ __launch_bounds__(256) void cvt_x(const float* __restrict__ x,
                                             unsigned short* __restrict__ xb, int n) {
  int i = (blockIdx.x * 256 + threadIdx.x) * 4;
  int stride = gridDim.x * 256 * 4;
  for (; i < n; i += stride) {
    f32x4 v = *(const f32x4*)(x + i);
    u16x4 o;
    o[0] = f2bf(v[0]); o[1] = f2bf(v[1]); o[2] = f2bf(v[2]); o[3] = f2bf(v[3]);
    *(u16x4*)(xb + i) = o;
  }
}

// ---------------- weight transpose+convert: Wt[n][k] = W[k][n], bf16 ----------------
__global__ __launch_bounds__(256) void wtrans(const float* W0, const float* W1,
                                              const float* W2, const float* W3,
                                              unsigned short* __restrict__ Wt) {
  const float* W = blockIdx.z == 0 ? W0 : blockIdx.z == 1 ? W1 : blockIdx.z == 2 ? W2 : W3;
  unsigned short* out = Wt + (size_t)blockIdx.z * DIM * DIM;
  const int n0 = blockIdx.x * 64, k0 = blockIdx.y * 64;
  __shared__ unsigned short t[64][68];
  const int tid = threadIdx.x;
#pragma unroll
  for (int i = 0; i < 16; i++) {
    int idx = tid + i * 256;
    int r = idx >> 6, c = idx & 63;            // r: k-dir, c: n-dir
    t[r][c] = f2bf(W[(size_t)(k0 + r) * DIM + n0 + c]);
  }
  __syncthreads();
#pragma unroll
  for (int i = 0; i < 16; i++) {
    int idx = tid + i * 256;
    int r = idx >> 6, c = idx & 63;            // r: n-dir, c: k-dir
    out[(size_t)(n0 + r) * DIM + k0 + c] = t[c][r];
  }
}

// ---------------- GEMM: C[M][N] = A[M][K](bf16) @ Bt[N][K]^T(bf16) + bias, f32 out ----
// 128x128 tile, BK=64, 4 waves, 16x16x32 bf16 MFMA, global_load_lds w/ XOR swizzle.
__global__ __launch_bounds__(256) void gemm_bt(
    const unsigned short* __restrict__ A, const unsigned short* __restrict__ Bt,
    float* __restrict__ C,
    const float* __restrict__ b0, const float* __restrict__ b1, const float* __restrict__ b2,
    int M, int N, int K, int biasMode) {
  __shared__ __align__(16) unsigned short As[128 * 64];
  __shared__ __align__(16) unsigned short Bs[128 * 64];
  const int tid = threadIdx.x;
  const int lane = tid & 63, w = tid >> 6;
  const int wr = w >> 1, wc = w & 1;
  const int l15 = lane & 15, g4 = lane >> 4;
  const int m0 = blockIdx.y * 128, n0 = blockIdx.x * 128;

  f32x4 acc[4][4];
#pragma unroll
  for (int i = 0; i < 4; i++)
#pragma unroll
    for (int j = 0; j < 4; j++) acc[i][j] = (f32x4){0.f, 0.f, 0.f, 0.f};

  for (int kt = 0; kt < K; kt += 64) {
    __syncthreads();
#pragma unroll
    for (int i = 0; i < 4; i++) {   // A tile: 128 rows x 64 bf16, 8x16B chunks/row
      int c = tid + i * 256;
      int row = c >> 3, g = c & 7;
      int gs = g ^ (row & 7);       // pre-swizzled source so swizzled read is conflict-free
      gload_lds16(A + (size_t)(m0 + row) * K + kt + gs * 8, As + c * 8);
    }
#pragma unroll
    for (int i = 0; i < 4; i++) {   // B^T tile
      int c = tid + i * 256;
      int row = c >> 3, g = c & 7;
      int gs = g ^ (row & 7);
      gload_lds16(Bt + (size_t)(n0 + row) * K + kt + gs * 8, Bs + c * 8);
    }
    __syncthreads();
#pragma unroll
    for (int kk = 0; kk < 2; kk++) {
      s16x8 af[4], bfr[4];
#pragma unroll
      for (int m = 0; m < 4; m++) {
        int row = wr * 64 + m * 16 + l15;
        int off = row * 128 + ((kk * 64 + g4 * 16) ^ ((row & 7) << 4));
        af[m] = *(const s16x8*)((const char*)As + off);
      }
#pragma unroll
      for (int n = 0; n < 4; n++) {
        int row = wc * 64 + n * 16 + l15;
        int off = row * 128 + ((kk * 64 + g4 * 16) ^ ((row & 7) << 4));
        bfr[n] = *(const s16x8*)((const char*)Bs + off);
      }
#pragma unroll
      for (int m = 0; m < 4; m++)
#pragma unroll
        for (int n = 0; n < 4; n++)
          acc[m][n] = __builtin_amdgcn_mfma_f32_16x16x32_bf16(af[m], bfr[n], acc[m][n], 0, 0, 0);
    }
  }
#pragma unroll
  for (int m = 0; m < 4; m++)
#pragma unroll
    for (int n = 0; n < 4; n++)
#pragma unroll
      for (int r = 0; r < 4; r++) {
        int grow = m0 + wr * 64 + m * 16 + g4 * 4 + r;
        int gcol = n0 + wc * 64 + n * 16 + l15;
        float bias = (biasMode == 1)
                         ? b0[gcol]
                         : (gcol < 1536 ? b0[gcol]
                                        : (gcol < 3072 ? b1[gcol - 1536] : b2[gcol - 3072]));
        C[(size_t)grow * N + gcol] = acc[m][n][r] + bias;
      }
}

// ---------------- RMSNorm (over full 1536) + RoPE -> qb/kb [b][h][l][d] bf16 -------
__global__ __launch_bounds__(256) void rmsrope(
    const float* __restrict__ qkv,   // [4096][4608]
    const float* __restrict__ gq, const float* __restrict__ gk,
    const int* __restrict__ grid_sizes,
    const float* __restrict__ fcos, const float* __restrict__ fsin,
    unsigned short* __restrict__ qb, unsigned short* __restrict__ kb) {
  const int t = blockIdx.x;                  // token 0..4095
  const int b = t >> 11, l = t & 2047;
  const int tid = threadIdx.x;
  __shared__ float qrow[1536], krow[1536];
  __shared__ float red[8];
  const float* rq = qkv + (size_t)t * 4608;
  const float* rk = rq + 1536;
  float sq = 0.f, sk = 0.f;
  for (int i = tid; i < 1536; i += 256) {
    float a = rq[i]; qrow[i] = a; sq += a * a;
    float c = rk[i]; krow[i] = c; sk += c * c;
  }
  for (int o = 32; o; o >>= 1) { sq += __shfl_down(sq, o); sk += __shfl_down(sk, o); }
  if ((tid & 63) == 0) { red[tid >> 6] = sq; red[4 + (tid >> 6)] = sk; }
  __syncthreads();
  const float rsq = rsqrtf((red[0] + red[1] + red[2] + red[3]) * (1.f / 1536.f) + 1e-6f);
  const float rsk = rsqrtf((red[4] + red[5] + red[6] + red[7]) * (1.f / 1536.f) + 1e-6f);
  const int fg = grid_sizes[b * 3 + 0], hg = grid_sizes[b * 3 + 1], wg = grid_sizes[b * 3 + 2];
  const int hw = hg * wg;
  const bool valid = l < fg * hw;
  const int fi = valid ? l / hw : 0;
  const int hi = valid ? (l / wg) % hg : 0;
  const int wi = valid ? l % wg : 0;
  const size_t obase = (((size_t)b * HEADS) * LSEQ + l) * HD;
  for (int i = tid; i < HEADS * 64; i += 256) {
    int hd = i >> 6, j = i & 63;
    float c, s;
    if (valid) {
      int idx = j < 22 ? fi : (j < 43 ? hi : wi);
      c = fcos[idx * 64 + j]; s = fsin[idx * 64 + j];
    } else { c = 1.f; s = 0.f; }
    int col = hd * 128 + 2 * j;
    size_t o = obase + (size_t)hd * LSEQ * HD + 2 * j;
    float xr = qrow[col] * rsq * gq[col];
    float xi = qrow[col + 1] * rsq * gq[col + 1];
    qb[o]     = f2bf(xr * c - xi * s);
    qb[o + 1] = f2bf(xr * s + xi * c);
    xr = krow[col] * rsk * gk[col];
    xi = krow[col + 1] * rsk * gk[col + 1];
    kb[o]     = f2bf(xr * c - xi * s);
    kb[o + 1] = f2bf(xr * s + xi * c);
  }
}

// ---------------- V transpose: vt[b][h][d][l] bf16 ----------------
__global__ __launch_bounds__(256) void vtrans(const float* __restrict__ qkv,
                                              unsigned short* __restrict__ vt) {
  const int lt = blockIdx.x, h = blockIdx.y, b = blockIdx.z;
  const int l0 = lt * 64;
  __shared__ unsigned short tile[64][130];
  const int tid = threadIdx.x;
#pragma unroll
  for (int i = 0; i < 32; i++) {
    int idx = tid + i * 256;
    int tk = idx >> 7, d = idx & 127;
    float v = qkv[(size_t)(b * 2048 + l0 + tk) * 4608 + 3072 + h * 128 + d];
    tile[tk][d] = f2bf(v);
  }
  __syncthreads();
  const size_t ob = (((size_t)b * HEADS + h) * HD) * LSEQ + l0;
#pragma unroll
  for (int i = 0; i < 32; i++) {
    int idx = tid + i * 256;
    int d = idx >> 6, tk = idx & 63;
    vt[ob + (size_t)d * LSEQ + tk] = tile[tk][d];
  }
}

// ---------------- flash attention ----------------
__global__ __launch_bounds__(256) void flash(
    const unsigned short* __restrict__ qb, const unsigned short* __restrict__ kb,
    const unsigned short* __restrict__ vt, const int* __restrict__ seq_lens,
    unsigned short* __restrict__ ob) {
  const int qt = blockIdx.x, h = blockIdx.y, b = blockIdx.z;
  const int tid = threadIdx.x, lane = tid & 63, w = tid >> 6;
  const int l15 = lane & 15, g4 = lane >> 4;
  __shared__ __align__(16) unsigned short Ks[64 * 128];   // [key][d], swizzled
  __shared__ __align__(16) unsigned short Vs[128 * 64];   // [d][key], swizzled
  __shared__ __align__(16) unsigned short Pl[4][16 * 64]; // per-wave P, swizzled
  const size_t bh = (size_t)b * HEADS + h;
  const int q0 = qt * 64 + w * 16;
  s16x8 qf[4];
  {
    const unsigned short* qp = qb + (bh * LSEQ + q0 + l15) * HD;
#pragma unroll
    for (int c = 0; c < 4; c++) qf[c] = *(const s16x8*)(qp + c * 32 + g4 * 8);
  }
  f32x4 acc[8];
#pragma unroll
  for (int i = 0; i < 8; i++) acc[i] = (f32x4){0.f, 0.f, 0.f, 0.f};
  float mrow[4] = {-1e30f, -1e30f, -1e30f, -1e30f};
  float ls[4] = {0.f, 0.f, 0.f, 0.f};
  const int ntile = seq_lens[b] >> 6;
  const float scale = 0.08838834764831845f;

  for (int kt = 0; kt < ntile; kt++) {
    __syncthreads();
    const int k0 = kt * 64;
#pragma unroll
    for (int i = 0; i < 4; i++) {    // K tile: 64 keys x 128 d, 16 chunks/row
      int c = tid + i * 256;
      int row = c >> 4, seg = c & 15;
      int ss = seg ^ (row & 7);
      gload_lds16(kb + (bh * LSEQ + k0 + row) * HD + ss * 8, Ks + c * 8);
    }
#pragma unroll
    for (int i = 0; i < 4; i++) {    // V tile: 128 d x 64 keys, 8 chunks/row
      int c = tid + i * 256;
      int row = c >> 3, seg = c & 7;
      int ss = seg ^ (row & 7);
      gload_lds16(vt + (bh * HD + row) * LSEQ + k0 + ss * 8, Vs + c * 8);
    }
    __syncthreads();
    // QK^T: S[q][key], 16q x 64key per wave
    f32x4 sv[4];
#pragma unroll
    for (int n = 0; n < 4; n++) {
      f32x4 a = (f32x4){0.f, 0.f, 0.f, 0.f};
      int key = n * 16 + l15;
#pragma unroll
      for (int c = 0; c < 4; c++) {
        int off = key * 256 + ((c * 64 + g4 * 16) ^ ((key & 7) << 4));
        s16x8 kf = *(const s16x8*)((const char*)Ks + off);
        a = __builtin_amdgcn_mfma_f32_16x16x32_bf16(qf[c], kf, a, 0, 0, 0);
      }
      sv[n] = a;
    }
    // online softmax per q-row r; write P to per-wave LDS
    unsigned short* pw = (unsigned short*)Pl[w];
#pragma unroll
    for (int r = 0; r < 4; r++) {
      float v0 = sv[0][r] * scale, v1 = sv[1][r] * scale;
      float v2 = sv[2][r] * scale, v3 = sv[3][r] * scale;
      float mx = fmaxf(fmaxf(v0, v1), fmaxf(v2, v3));
#pragma unroll
      for (int o = 8; o; o >>= 1) mx = fmaxf(mx, __shfl_xor(mx, o));
      float mnew = fmaxf(mrow[r], mx);
      float alpha = __expf(mrow[r] - mnew);
      float p0 = __expf(v0 - mnew), p1 = __expf(v1 - mnew);
      float p2 = __expf(v2 - mnew), p3 = __expf(v3 - mnew);
      float rs = p0 + p1 + p2 + p3;
#pragma unroll
      for (int o = 8; o; o >>= 1) rs += __shfl_xor(rs, o);
      ls[r] = ls[r] * alpha + rs;
      mrow[r] = mnew;
#pragma unroll
      for (int dn = 0; dn < 8; dn++) acc[dn][r] *= alpha;
      int q = g4 * 4 + r;
      int sw = (q & 7) << 4;
      *(unsigned short*)((char*)pw + q * 128 + (((0 * 16 + l15) * 2) ^ sw)) = f2bf(p0);
      *(unsigned short*)((char*)pw + q * 128 + (((1 * 16 + l15) * 2) ^ sw)) = f2bf(p1);
      *(unsigned short*)((char*)pw + q * 128 + (((2 * 16 + l15) * 2) ^ sw)) = f2bf(p2);
      *(unsigned short*)((char*)pw + q * 128 + (((3 * 16 + l15) * 2) ^ sw)) = f2bf(p3);
    }
    // PV: A=P (rows q), B=V^T (cols d, k=key contiguous)
    s16x8 pa[2];
#pragma unroll
    for (int kk = 0; kk < 2; kk++) {
      int off = l15 * 128 + ((kk * 64 + g4 * 16) ^ ((l15 & 7) << 4));
      pa[kk] = *(const s16x8*)((const char*)pw + off);
    }
#pragma unroll
    for (int dn = 0; dn < 8; dn++) {
      int d = dn * 16 + l15;
#pragma unroll
      for (int kk = 0; kk < 2; kk++) {
        int off = d * 128 + ((kk * 64 + g4 * 16) ^ ((d & 7) << 4));
        s16x8 vf = *(const s16x8*)((const char*)Vs + off);
        acc[dn] = __builtin_amdgcn_mfma_f32_16x16x32_bf16(pa[kk], vf, acc[dn], 0, 0, 0);
      }
    }
  }
  // epilogue: O /= l, write [token][h*128+d] bf16
  float inv[4];
#pragma unroll
  for (int r = 0; r < 4; r++) inv[r] = 1.f / ls[r];
#pragma unroll
  for (int dn = 0; dn < 8; dn++)
#pragma unroll
    for (int r = 0; r < 4; r++) {
      int tok = b * LSEQ + qt * 64 + w * 16 + g4 * 4 + r;
      int col = h * HD + dn * 16 + l15;
      ob[(size_t)tok * DIM + col] = f2bf(acc[dn][r] * inv[r]);
    }
}

// ---------------- launch ----------------
extern "C" void kernel_launch(void* const* d_in, const int* in_sizes, int n_in,
                              void* d_out, int out_size, void* d_ws, size_t ws_size,
                              hipStream_t stream) {
  const float* x    = (const float*)d_in[0];
  const int*   seq  = (const int*)d_in[1];
  const int*   grids= (const int*)d_in[2];
  const float* fcos = (const float*)d_in[3];
  const float* fsin = (const float*)d_in[4];
  const float* Wq   = (const float*)d_in[5];
  const float* bq   = (const float*)d_in[6];
  const float* Wk   = (const float*)d_in[7];
  const float* bk   = (const float*)d_in[8];
  const float* Wv   = (const float*)d_in[9];
  const float* bv   = (const float*)d_in[10];
  const float* Wo   = (const float*)d_in[11];
  const float* bo   = (const float*)d_in[12];
  const float* gq   = (const float*)d_in[13];
  const float* gk   = (const float*)d_in[14];

  char* ws = (char*)d_ws;
  unsigned short* xb  = (unsigned short*)(ws);                    // 12.58 MB (reused as attn-out)
  unsigned short* Wt  = (unsigned short*)(ws + 12582912);         // 18.87 MB (4 transposed planes)
  float*          qkv = (float*)(ws + 31457280);                  // 75.50 MB [4096][4608]
  unsigned short* qbb = (unsigned short*)(ws + 106954752);        // 12.58 MB
  unsigned short* kbb = (unsigned short*)(ws + 119537664);        // 12.58 MB
  unsigned short* vt  = (unsigned short*)d_out;                   // scratch; overwritten by final GEMM
  unsigned short* obb = xb;                                       // attn-out, aliases xb (dead by then)
  float* out = (float*)d_out;

  cvt_x<<<1024, 256, 0, stream>>>(x, xb, NTOK * DIM);
  wtrans<<<dim3(24, 24, 4), 256, 0, stream>>>(Wq, Wk, Wv, Wo, Wt);
  gemm_bt<<<dim3(36, 32), 256, 0, stream>>>(xb, Wt, qkv, bq, bk, bv, NTOK, 3 * DIM, DIM, 0);
  rmsrope<<<NTOK, 256, 0, stream>>>(qkv, gq, gk, grids, fcos, fsin, qbb, kbb);
  vtrans<<<dim3(32, 12, 2), 256, 0, stream>>>(qkv, vt);
  flash<<<dim3(32, 12, 2), 256, 0, stream>>>(qbb, kbb, vt, seq, obb);
  gemm_bt<<<dim3(12, 32), 256, 0, stream>>>(obb, Wt + (size_t)3 * DIM * DIM, out,
                                            bo, bo, bo, NTOK, DIM, DIM, 1);
}

// Round 3
// 247.730 us; speedup vs baseline: 1.2694x; 1.2694x over previous
//
#include <hip/hip_runtime.h>
#include <hip/hip_bf16.h>

#define DIM   1536
#define HEADS 12
#define HD    128
#define LSEQ  2048
#define NB    2
#define NTOK  (NB*LSEQ)   // 4096

using f32x4 = __attribute__((ext_vector_type(4))) float;
using s16x8 = __attribute__((ext_vector_type(8))) short;
using u16x4 = __attribute__((ext_vector_type(4))) unsigned short;

__device__ __forceinline__ unsigned short f2bf(float f) {
  unsigned int u = __builtin_bit_cast(unsigned int, f);
  u += 0x7fffu + ((u >> 16) & 1u);   // RNE
  return (unsigned short)(u >> 16);
}
__device__ __forceinline__ float bf2f(unsigned short u) {
  return __builtin_bit_cast(float, (unsigned int)u << 16);
}
__device__ __forceinline__ void gload_lds16(const void* g, void* l) {
  __builtin_amdgcn_global_load_lds(
      (__attribute__((address_space(1))) void*)const_cast<void*>(g),
      (__attribute__((address_space(3))) void*)l,
      16, 0, 0);
}

// ---------------- convert x -> bf16 ----------------
__global__ __launch_bounds__(256) void cvt_x(const float* __restrict__ x,
                                             unsigned short* __restrict__ xb, int n) {
  int i = (blockIdx.x * 256 + threadIdx.x) * 4;
  int stride = gridDim.x * 256 * 4;
  for (; i < n; i += stride) {
    f32x4 v = *(const f32x4*)(x + i);
    u16x4 o;
    o[0] = f2bf(v[0]); o[1] = f2bf(v[1]); o[2] = f2bf(v[2]); o[3] = f2bf(v[3]);
    *(u16x4*)(xb + i) = o;
  }
}

// ---------------- weight transpose+convert: Wt[n][k] = W[k][n], bf16 ----------------
__global__ __launch_bounds__(256) void wtrans(const float* W0, const float* W1,
                                              const float* W2, const float* W3,
                                              unsigned short* __restrict__ Wt) {
  const float* W = blockIdx.z == 0 ? W0 : blockIdx.z == 1 ? W1 : blockIdx.z == 2 ? W2 : W3;
  unsigned short* out = Wt + (size_t)blockIdx.z * DIM * DIM;
  const int n0 = blockIdx.x * 64, k0 = blockIdx.y * 64;
  __shared__ unsigned short t[64][68];
  const int tid = threadIdx.x;
#pragma unroll
  for (int i = 0; i < 16; i++) {
    int idx = tid + i * 256;
    int r = idx >> 6, c = idx & 63;
    t[r][c] = f2bf(W[(size_t)(k0 + r) * DIM + n0 + c]);
  }
  __syncthreads();
#pragma unroll
  for (int i = 0; i < 16; i++) {
    int idx = tid + i * 256;
    int r = idx >> 6, c = idx & 63;
    out[(size_t)(n0 + r) * DIM + k0 + c] = t[c][r];
  }
}

// ---------------- GEMM: C[M][N] = A @ Bt^T + bias; f32 or bf16 out ----------------
__global__ __launch_bounds__(256) void gemm_bt(
    const unsigned short* __restrict__ A, const unsigned short* __restrict__ Bt,
    void* __restrict__ Cv,
    const float* __restrict__ b0, const float* __restrict__ b1, const float* __restrict__ b2,
    int M, int N, int K, int biasMode, int outBf16) {
  __shared__ __align__(16) unsigned short As[128 * 64];
  __shared__ __align__(16) unsigned short Bs[128 * 64];
  const int tid = threadIdx.x;
  const int lane = tid & 63, w = tid >> 6;
  const int wr = w >> 1, wc = w & 1;
  const int l15 = lane & 15, g4 = lane >> 4;
  // XCD-aware bijective swizzle (nwg % 8 == 0 for both launch configs)
  const int nwg = gridDim.x * gridDim.y;
  const int bidf = blockIdx.y * gridDim.x + blockIdx.x;
  const int cpx = nwg >> 3;
  const int sw = (bidf & 7) * cpx + (bidf >> 3);
  const int m0 = (sw / gridDim.x) * 128, n0 = (sw % gridDim.x) * 128;

  f32x4 acc[4][4];
#pragma unroll
  for (int i = 0; i < 4; i++)
#pragma unroll
    for (int j = 0; j < 4; j++) acc[i][j] = (f32x4){0.f, 0.f, 0.f, 0.f};

  for (int kt = 0; kt < K; kt += 64) {
    __syncthreads();
#pragma unroll
    for (int i = 0; i < 4; i++) {
      int c = tid + i * 256;
      int row = c >> 3, g = c & 7;
      int gs = g ^ (row & 7);
      gload_lds16(A + (size_t)(m0 + row) * K + kt + gs * 8, As + c * 8);
    }
#pragma unroll
    for (int i = 0; i < 4; i++) {
      int c = tid + i * 256;
      int row = c >> 3, g = c & 7;
      int gs = g ^ (row & 7);
      gload_lds16(Bt + (size_t)(n0 + row) * K + kt + gs * 8, Bs + c * 8);
    }
    __syncthreads();
#pragma unroll
    for (int kk = 0; kk < 2; kk++) {
      s16x8 af[4], bfr[4];
#pragma unroll
      for (int m = 0; m < 4; m++) {
        int row = wr * 64 + m * 16 + l15;
        int off = row * 128 + ((kk * 64 + g4 * 16) ^ ((row & 7) << 4));
        af[m] = *(const s16x8*)((const char*)As + off);
      }
#pragma unroll
      for (int n = 0; n < 4; n++) {
        int row = wc * 64 + n * 16 + l15;
        int off = row * 128 + ((kk * 64 + g4 * 16) ^ ((row & 7) << 4));
        bfr[n] = *(const s16x8*)((const char*)Bs + off);
      }
#pragma unroll
      for (int m = 0; m < 4; m++)
#pragma unroll
        for (int n = 0; n < 4; n++)
          acc[m][n] = __builtin_amdgcn_mfma_f32_16x16x32_bf16(af[m], bfr[n], acc[m][n], 0, 0, 0);
    }
  }
#pragma unroll
  for (int m = 0; m < 4; m++)
#pragma unroll
    for (int n = 0; n < 4; n++)
#pragma unroll
      for (int r = 0; r < 4; r++) {
        int grow = m0 + wr * 64 + m * 16 + g4 * 4 + r;
        int gcol = n0 + wc * 64 + n * 16 + l15;
        float bias = (biasMode == 1)
                         ? b0[gcol]
                         : (gcol < 1536 ? b0[gcol]
                                        : (gcol < 3072 ? b1[gcol - 1536] : b2[gcol - 3072]));
        float val = acc[m][n][r] + bias;
        if (outBf16) ((unsigned short*)Cv)[(size_t)grow * N + gcol] = f2bf(val);
        else         ((float*)Cv)[(size_t)grow * N + gcol] = val;
      }
}

// ---------------- RMSNorm + RoPE (qkv bf16); q pre-scaled by 1/sqrt(d) -------
__global__ __launch_bounds__(256) void rmsrope(
    const unsigned short* __restrict__ qkvb,   // [4096][4608] bf16
    const float* __restrict__ gq, const float* __restrict__ gk,
    const int* __restrict__ grid_sizes,
    const float* __restrict__ fcos, const float* __restrict__ fsin,
    unsigned short* __restrict__ qb, unsigned short* __restrict__ kb) {
  const int t = blockIdx.x;
  const int b = t >> 11, l = t & 2047;
  const int tid = threadIdx.x;
  __shared__ float qrow[1536], krow[1536];
  __shared__ float red[8];
  const unsigned short* rq = qkvb + (size_t)t * 4608;
  const unsigned short* rk = rq + 1536;
  float sq = 0.f, sk = 0.f;
  if (tid < 192) {
    s16x8 vq = *(const s16x8*)(rq + tid * 8);
    s16x8 vk = *(const s16x8*)(rk + tid * 8);
#pragma unroll
    for (int j = 0; j < 8; j++) {
      float a = bf2f((unsigned short)vq[j]); qrow[tid * 8 + j] = a; sq += a * a;
      float c = bf2f((unsigned short)vk[j]); krow[tid * 8 + j] = c; sk += c * c;
    }
  }
  for (int o = 32; o; o >>= 1) { sq += __shfl_down(sq, o); sk += __shfl_down(sk, o); }
  if ((tid & 63) == 0) { red[tid >> 6] = sq; red[4 + (tid >> 6)] = sk; }
  __syncthreads();
  const float rsq = rsqrtf((red[0] + red[1] + red[2] + red[3]) * (1.f / 1536.f) + 1e-6f);
  const float rsk = rsqrtf((red[4] + red[5] + red[6] + red[7]) * (1.f / 1536.f) + 1e-6f);
  const float QS = 0.08838834764831845f;   // 1/sqrt(128), folded into q
  const int fg = grid_sizes[b * 3 + 0], hg = grid_sizes[b * 3 + 1], wg = grid_sizes[b * 3 + 2];
  const int hw = hg * wg;
  const bool valid = l < fg * hw;
  const int fi = valid ? l / hw : 0;
  const int hi = valid ? (l / wg) % hg : 0;
  const int wi = valid ? l % wg : 0;
  const size_t obase = (((size_t)b * HEADS) * LSEQ + l) * HD;
  for (int i = tid; i < HEADS * 64; i += 256) {
    int hd = i >> 6, j = i & 63;
    float c, s;
    if (valid) {
      int idx = j < 22 ? fi : (j < 43 ? hi : wi);
      c = fcos[idx * 64 + j]; s = fsin[idx * 64 + j];
    } else { c = 1.f; s = 0.f; }
    int col = hd * 128 + 2 * j;
    size_t o = obase + (size_t)hd * LSEQ * HD + 2 * j;
    float xr = qrow[col] * rsq * gq[col];
    float xi = qrow[col + 1] * rsq * gq[col + 1];
    float q0 = (xr * c - xi * s) * QS, q1 = (xr * s + xi * c) * QS;
    *(unsigned int*)(qb + o) = (unsigned int)f2bf(q0) | ((unsigned int)f2bf(q1) << 16);
    xr = krow[col] * rsk * gk[col];
    xi = krow[col + 1] * rsk * gk[col + 1];
    *(unsigned int*)(kb + o) =
        (unsigned int)f2bf(xr * c - xi * s) | ((unsigned int)f2bf(xr * s + xi * c) << 16);
  }
}

// ---------------- V transpose: vt[b][h][d][l] bf16 (bf16 input) ----------------
__global__ __launch_bounds__(256) void vtrans(const unsigned short* __restrict__ qkvb,
                                              unsigned short* __restrict__ vt) {
  const int lt = blockIdx.x, h = blockIdx.y, b = blockIdx.z;
  const int l0 = lt * 64;
  __shared__ unsigned short tile[64][130];
  const int tid = threadIdx.x;
#pragma unroll
  for (int i = 0; i < 4; i++) {
    int idx = tid + i * 256;
    int tk = idx >> 4, dc = (idx & 15) * 8;
    s16x8 v = *(const s16x8*)(qkvb + (size_t)(b * 2048 + l0 + tk) * 4608 + 3072 + h * 128 + dc);
#pragma unroll
    for (int j = 0; j < 8; j++) tile[tk][dc + j] = (unsigned short)v[j];
  }
  __syncthreads();
  const size_t ob = (((size_t)b * HEADS + h) * HD) * LSEQ + l0;
#pragma unroll
  for (int i = 0; i < 4; i++) {
    int idx = tid + i * 256;
    int d = idx >> 3, ck = (idx & 7) * 8;
    s16x8 o;
#pragma unroll
    for (int j = 0; j < 8; j++) o[j] = (short)tile[ck + j][d];
    *(s16x8*)(vt + ob + (size_t)d * LSEQ + ck) = o;
  }
}

// ---------------- flash attention: 2-phase prefetch w/ __syncthreads ----------
__global__ __launch_bounds__(256) void flash(
    const unsigned short* __restrict__ qb, const unsigned short* __restrict__ kb,
    const unsigned short* __restrict__ vt, const int* __restrict__ seq_lens,
    unsigned short* __restrict__ ob) {
  const int qt = blockIdx.x, h = blockIdx.y, b = blockIdx.z;
  const int tid = threadIdx.x, lane = tid & 63, w = tid >> 6;
  const int l15 = lane & 15, g4 = lane >> 4;
  __shared__ __align__(16) unsigned short Ks[64 * 128];   // [key][d], swizzled
  __shared__ __align__(16) unsigned short Vs[128 * 64];   // [d][key], swizzled
  __shared__ __align__(16) unsigned short Pl[4][16 * 64]; // per-wave P [q][key], swizzled
  const size_t bh = (size_t)b * HEADS + h;
  const int q0 = qt * 64 + w * 16;
  s16x8 qf[4];
  {
    const unsigned short* qp = qb + (bh * LSEQ + q0 + l15) * HD;
#pragma unroll
    for (int c = 0; c < 4; c++) qf[c] = *(const s16x8*)(qp + c * 32 + g4 * 8);
  }
  f32x4 acc[8];
#pragma unroll
  for (int i = 0; i < 8; i++) acc[i] = (f32x4){0.f, 0.f, 0.f, 0.f};
  float mrow[4] = {-1e30f, -1e30f, -1e30f, -1e30f};
  float ls[4] = {0.f, 0.f, 0.f, 0.f};
  const int ntile = seq_lens[b] >> 6;
  char* pw = (char*)&Pl[w][0];

  // prologue: stage K(0)
#pragma unroll
  for (int i = 0; i < 4; i++) {
    int c = tid + i * 256, row = c >> 4, seg = c & 15, ss = seg ^ (row & 7);
    gload_lds16(kb + (bh * LSEQ + row) * HD + ss * 8, &Ks[0] + c * 8);
  }

  for (int kt = 0; kt < ntile; kt++) {
    const int k0 = kt * 64;
    // sync A: K(t) drained; all waves done PV(t-1) reads of Vs
    __syncthreads();
    // issue V(t): latency hides under QK+softmax
#pragma unroll
    for (int i = 0; i < 4; i++) {
      int c = tid + i * 256, row = c >> 3, seg = c & 7, ss = seg ^ (row & 7);
      gload_lds16(vt + (bh * HD + row) * LSEQ + k0 + ss * 8, &Vs[0] + c * 8);
    }
    // QK^T
    f32x4 sv[4];
    __builtin_amdgcn_s_setprio(1);
#pragma unroll
    for (int n = 0; n < 4; n++) {
      f32x4 a = (f32x4){0.f, 0.f, 0.f, 0.f};
      int key = n * 16 + l15;
#pragma unroll
      for (int c = 0; c < 4; c++) {
        int off = key * 256 + ((c * 64 + g4 * 16) ^ ((key & 7) << 4));
        s16x8 kf = *(const s16x8*)((const char*)Ks + off);
        a = __builtin_amdgcn_mfma_f32_16x16x32_bf16(qf[c], kf, a, 0, 0, 0);
      }
      sv[n] = a;
    }
    __builtin_amdgcn_s_setprio(0);
    // online softmax with defer-max (scores pre-scaled via Q)
    float alpha_[4];
    bool anyGrow = false;
#pragma unroll
    for (int r = 0; r < 4; r++) {
      float v0 = sv[0][r], v1 = sv[1][r], v2 = sv[2][r], v3 = sv[3][r];
      float mx = fmaxf(fmaxf(v0, v1), fmaxf(v2, v3));
#pragma unroll
      for (int o = 8; o; o >>= 1) mx = fmaxf(mx, __shfl_xor(mx, o));
      bool grow = mx > mrow[r] + 8.0f;
      float mnew = grow ? mx : mrow[r];
      float p0 = __expf(v0 - mnew), p1 = __expf(v1 - mnew);
      float p2 = __expf(v2 - mnew), p3 = __expf(v3 - mnew);
      float rs = p0 + p1 + p2 + p3;
#pragma unroll
      for (int o = 8; o; o >>= 1) rs += __shfl_xor(rs, o);
      float alpha = grow ? __expf(mrow[r] - mnew) : 1.f;
      ls[r] = ls[r] * alpha + rs;
      mrow[r] = mnew; alpha_[r] = alpha; anyGrow |= grow;
      // P store (R1-verified): [q][key] swizzled
      int q = g4 * 4 + r;
      int swz = (q & 7) << 4;
      *(unsigned short*)(pw + q * 128 + ((2 * (0 * 16 + l15)) ^ swz)) = f2bf(p0);
      *(unsigned short*)(pw + q * 128 + ((2 * (1 * 16 + l15)) ^ swz)) = f2bf(p1);
      *(unsigned short*)(pw + q * 128 + ((2 * (2 * 16 + l15)) ^ swz)) = f2bf(p2);
      *(unsigned short*)(pw + q * 128 + ((2 * (3 * 16 + l15)) ^ swz)) = f2bf(p3);
    }
    if (__any((int)anyGrow)) {
#pragma unroll
      for (int dn = 0; dn < 8; dn++)
#pragma unroll
        for (int r = 0; r < 4; r++) acc[dn][r] *= alpha_[r];
    }
    // sync B: V(t) ready; P stores visible; all waves done QK(t) reads of Ks
    __syncthreads();
    // issue K(t+1): latency hides under PV + next sync A
    if (kt + 1 < ntile) {
#pragma unroll
      for (int i = 0; i < 4; i++) {
        int c = tid + i * 256, row = c >> 4, seg = c & 15, ss = seg ^ (row & 7);
        gload_lds16(kb + (bh * LSEQ + k0 + 64 + row) * HD + ss * 8, &Ks[0] + c * 8);
      }
    }
    // P read (R1-verified): A fragment, row q=l15, k=kk*32+g4*8+e
    s16x8 pa[2];
#pragma unroll
    for (int kk = 0; kk < 2; kk++) {
      int off = l15 * 128 + ((kk * 64 + g4 * 16) ^ ((l15 & 7) << 4));
      pa[kk] = *(const s16x8*)(pw + off);
    }
    // PV
    __builtin_amdgcn_s_setprio(1);
#pragma unroll
    for (int dn = 0; dn < 8; dn++) {
      int d = dn * 16 + l15;
      int off0 = d * 128 + ((g4 * 16) ^ ((d & 7) << 4));
      int off1 = d * 128 + ((64 + g4 * 16) ^ ((d & 7) << 4));
      s16x8 vf0 = *(const s16x8*)((const char*)Vs + off0);
      s16x8 vf1 = *(const s16x8*)((const char*)Vs + off1);
      acc[dn] = __builtin_amdgcn_mfma_f32_16x16x32_bf16(pa[0], vf0, acc[dn], 0, 0, 0);
      acc[dn] = __builtin_amdgcn_mfma_f32_16x16x32_bf16(pa[1], vf1, acc[dn], 0, 0, 0);
    }
    __builtin_amdgcn_s_setprio(0);
  }
  // epilogue
  float inv[4];
#pragma unroll
  for (int r = 0; r < 4; r++) inv[r] = 1.f / ls[r];
#pragma unroll
  for (int dn = 0; dn < 8; dn++)
#pragma unroll
    for (int r = 0; r < 4; r++) {
      int tok = b * LSEQ + qt * 64 + w * 16 + g4 * 4 + r;
      int col = h * HD + dn * 16 + l15;
      ob[(size_t)tok * DIM + col] = f2bf(acc[dn][r] * inv[r]);
    }
}

// ---------------- launch ----------------
extern "C" void kernel_launch(void* const* d_in, const int* in_sizes, int n_in,
                              void* d_out, int out_size, void* d_ws, size_t ws_size,
                              hipStream_t stream) {
  const float* x    = (const float*)d_in[0];
  const int*   seq  = (const int*)d_in[1];
  const int*   grids= (const int*)d_in[2];
  const float* fcos = (const float*)d_in[3];
  const float* fsin = (const float*)d_in[4];
  const float* Wq   = (const float*)d_in[5];
  const float* bq   = (const float*)d_in[6];
  const float* Wk   = (const float*)d_in[7];
  const float* bk   = (const float*)d_in[8];
  const float* Wv   = (const float*)d_in[9];
  const float* bv   = (const float*)d_in[10];
  const float* Wo   = (const float*)d_in[11];
  const float* bo   = (const float*)d_in[12];
  const float* gq   = (const float*)d_in[13];
  const float* gk   = (const float*)d_in[14];

  char* ws = (char*)d_ws;
  unsigned short* xb   = (unsigned short*)(ws);                  // 12.58 MB (reused as attn-out)
  unsigned short* Wt   = (unsigned short*)(ws + 12582912);       // 18.87 MB
  unsigned short* qkvb = (unsigned short*)(ws + 31457280);       // 37.75 MB [4096][4608] bf16
  unsigned short* qbb  = (unsigned short*)(ws + 69206016);       // 12.58 MB
  unsigned short* kbb  = (unsigned short*)(ws + 81788928);       // 12.58 MB
  unsigned short* vt   = (unsigned short*)d_out;                 // scratch; overwritten later
  unsigned short* obb  = xb;                                     // attn-out aliases xb
  float* out = (float*)d_out;

  cvt_x<<<1024, 256, 0, stream>>>(x, xb, NTOK * DIM);
  wtrans<<<dim3(24, 24, 4), 256, 0, stream>>>(Wq, Wk, Wv, Wo, Wt);
  gemm_bt<<<dim3(36, 32), 256, 0, stream>>>(xb, Wt, qkvb, bq, bk, bv, NTOK, 3 * DIM, DIM, 0, 1);
  rmsrope<<<NTOK, 256, 0, stream>>>(qkvb, gq, gk, grids, fcos, fsin, qbb, kbb);
  vtrans<<<dim3(32, 12, 2), 256, 0, stream>>>(qkvb, vt);
  flash<<<dim3(32, 12, 2), 256, 0, stream>>>(qbb, kbb, vt, seq, obb);
  gemm_bt<<<dim3(12, 32), 256, 0, stream>>>(obb, Wt + (size_t)3 * DIM * DIM, out,
                                            bo, bo, bo, NTOK, DIM, DIM, 1, 0);
}